// Round 10
// baseline (639.731 us; speedup 1.0000x reference)
//
#include <hip/hip_runtime.h>
#include <hip/hip_bf16.h>
#include <stdint.h>

#define TOKENS 8192
#define DDIM 1024
#define HDIM 4096
#define NEXP 8
#define MAXENT 16384
#define MAXTILES 72

typedef __attribute__((ext_vector_type(4))) float f32x4;
typedef __attribute__((ext_vector_type(8))) short bf16x8;
typedef __attribute__((ext_vector_type(4))) int i32x4;

__device__ __forceinline__ unsigned short f2bf(float f) {
  __hip_bfloat16 h = __float2bfloat16(f);
  return __builtin_bit_cast(unsigned short, h);
}

__device__ __forceinline__ void gload16(const void* g, void* l) {
  __builtin_amdgcn_global_load_lds(
      (const __attribute__((address_space(1))) unsigned int*)g,
      (__attribute__((address_space(3))) unsigned int*)l, 16, 0, 0);
}

__device__ __forceinline__ void bar0() {
  asm volatile("" ::: "memory");
  __builtin_amdgcn_s_barrier();
  asm volatile("" ::: "memory");
}

#define VMWAIT(N) asm volatile("s_waitcnt vmcnt(" #N ")" ::: "memory")

// ---------------- prep ----------------

__global__ void moe_count(const int* __restrict__ idx, int* __restrict__ meta) {
  int t = blockIdx.x * 256 + threadIdx.x;
  if (t >= TOKENS) return;
  int e0 = idx[2 * t], e1 = idx[2 * t + 1];
  atomicAdd(&meta[e0], 1);
  if (e1 != e0) atomicAdd(&meta[e1], 1);
}

__global__ void moe_scan(int* __restrict__ meta) {
  if (threadIdx.x != 0 || blockIdx.x != 0) return;
  int s = 0;
  for (int e = 0; e < NEXP; ++e) { meta[16 + e] = s; meta[32 + e] = s; s += meta[e]; }
  meta[16 + NEXP] = s;
  int nt = 0;
  for (int e = 0; e < NEXP; ++e) {
    int m = (meta[e] + 255) >> 8;  // 256-entry tiles
    for (int t = 0; t < m; ++t) meta[64 + nt++] = e | (t << 8);
  }
  meta[48] = nt;
}

__global__ void moe_scatter(const int* __restrict__ idx, const float* __restrict__ ew,
                            int* __restrict__ meta, int* __restrict__ etok,
                            float* __restrict__ ewgt, int* __restrict__ inv) {
  int t = blockIdx.x * 256 + threadIdx.x;
  if (t >= TOKENS) return;
  int e0 = idx[2 * t], e1 = idx[2 * t + 1];
  float a = ew[2 * t], b = ew[2 * t + 1];
  if (e0 == e1) {
    int p = atomicAdd(&meta[32 + e0], 1);
    etok[p] = t; ewgt[p] = a + b;
    inv[2 * t] = p; inv[2 * t + 1] = -1;
  } else {
    int p = atomicAdd(&meta[32 + e0], 1);
    etok[p] = t; ewgt[p] = a;
    int q = atomicAdd(&meta[32 + e1], 1);
    etok[q] = t; ewgt[q] = b;
    inv[2 * t] = p; inv[2 * t + 1] = q;
  }
}

// ---- gather x -> A-pretile pages: [page256][kt32][chunk16][lane64][8] bf16 ----

__global__ __launch_bounds__(256) void gather_pre(const float* __restrict__ x,
                                                  const int* __restrict__ etok,
                                                  const int* __restrict__ meta,
                                                  unsigned short* __restrict__ xgp) {
  int ntiles = meta[48];
  int page = blockIdx.x, kt = blockIdx.y;
  if (page >= ntiles) return;
  int te = meta[64 + page];
  int e = te & 255, mt = te >> 8;
  int ent0 = meta[16 + e] + mt * 256, lim = meta[16 + e + 1];
  int tid = threadIdx.x;
#pragma unroll
  for (int it = 0; it < 4; ++it) {
    int u = it * 256 + tid;
    int chunk = u >> 6, lane = u & 63;
    int ent = ent0 + chunk * 16 + (lane & 15);
    if (ent > lim - 1) ent = lim - 1;
    int tok = etok[ent];
    const float4* s = (const float4*)(x + (size_t)tok * DDIM + kt * 32 + ((lane >> 4) << 3));
    float4 a = s[0], b = s[1];
    union { unsigned short h[8]; i32x4 v; } o;
    o.h[0] = f2bf(a.x); o.h[1] = f2bf(a.y); o.h[2] = f2bf(a.z); o.h[3] = f2bf(a.w);
    o.h[4] = f2bf(b.x); o.h[5] = f2bf(b.y); o.h[6] = f2bf(b.z); o.h[7] = f2bf(b.w);
    ((i32x4*)xgp)[(size_t)(page * 32 + kt) * 1024 + u] = o.v;
  }
}

// ---- weights -> B-pretile: [e][nt256][kt32][chunk16][lane64][8] bf16 ----
__global__ __launch_bounds__(256) void pretile_w(const float* __restrict__ src,
                                                 unsigned short* __restrict__ dst,
                                                 int Kdim, int Ndim) {
  __shared__ unsigned short t16[64][266];
  int NB = Ndim >> 8, KB = Kdim >> 6;
  int bid = blockIdx.x;
  int kblk = bid % KB; int rest = bid / KB;
  int nblk = rest % NB; int e = rest / NB;
  const float* s = src + ((size_t)e * Kdim + ((size_t)kblk << 6)) * Ndim + ((size_t)nblk << 8);
  int tid = threadIdx.x;
  int cp = tid & 127, rh = tid >> 7;
#pragma unroll
  for (int rr = 0; rr < 32; ++rr) {
    int r = rh * 32 + rr;
    float2 v = *(const float2*)(s + (size_t)r * Ndim + 2 * cp);
    unsigned int pk = (unsigned int)f2bf(v.x) | ((unsigned int)f2bf(v.y) << 16);
    *(unsigned int*)&t16[r][2 * cp] = pk;
  }
  __syncthreads();
  int KT32 = Kdim >> 5;
#pragma unroll
  for (int it = 0; it < 8; ++it) {
    int u = it * 256 + tid;
    int kt2 = u >> 10, rem = u & 1023;
    int chunk = rem >> 6, lane = rem & 63;
    int nl = chunk * 16 + (lane & 15);
    int kl = kt2 * 32 + ((lane >> 4) << 3);
    union { unsigned short h[8]; i32x4 v; } o;
#pragma unroll
    for (int i = 0; i < 8; ++i) o.h[i] = t16[kl + i][nl];
    size_t idx = (((size_t)e * NB + nblk) * KT32 + kblk * 2 + kt2) * 1024 + rem;
    ((i32x4*)dst)[idx] = o.v;
  }
}

// ---- GEMM flatmm-hybrid: 256x256, BK=32, 8 waves (2Mx4N).
// A: LDS 4-slot ring (gload_lds, staged 2 ahead). B: direct global->register,
// double-buffered 1 K-tile ahead. One barrier + one VMWAIT(2) per K-tile.

#define LOADB(R0, R1, R2, R3, KT) do {                 \
    const char* _p = pB + ((size_t)(KT) << 14);        \
    R0 = *(const bf16x8*)(_p);                         \
    R1 = *(const bf16x8*)(_p + 1024);                  \
    R2 = *(const bf16x8*)(_p + 2048);                  \
    R3 = *(const bf16x8*)(_p + 3072); } while (0)

#define MFMA32(PA, B0_, B1_, B2_, B3_) do {            \
    __builtin_amdgcn_s_setprio(1);                     \
    _Pragma("unroll") for (int m = 0; m < 8; ++m) {    \
      bf16x8 a_ = *(const bf16x8*)((PA) + m * 1024);   \
      acc[m][0] = __builtin_amdgcn_mfma_f32_16x16x32_bf16(a_, B0_, acc[m][0], 0, 0, 0); \
      acc[m][1] = __builtin_amdgcn_mfma_f32_16x16x32_bf16(a_, B1_, acc[m][1], 0, 0, 0); \
      acc[m][2] = __builtin_amdgcn_mfma_f32_16x16x32_bf16(a_, B2_, acc[m][2], 0, 0, 0); \
      acc[m][3] = __builtin_amdgcn_mfma_f32_16x16x32_bf16(a_, B3_, acc[m][3], 0, 0, 0); \
    }                                                  \
    __builtin_amdgcn_s_setprio(0); } while (0)

template <int MODE>
__global__ __launch_bounds__(512, 2) void moe_gemm(
    const unsigned short* __restrict__ Apre,  // pages [*][AKT][16KB]
    const unsigned short* __restrict__ Bpre,  // [e][BtNT][BtKT][16KB]
    const float* __restrict__ bias,
    const int* __restrict__ meta,
    const float* __restrict__ ewgt,
    unsigned short* __restrict__ Hbuf,
    float* __restrict__ Ybuf,
    int AKT, int BtNT, int BtKT, int ntg0, int kt0B,
    int nk, int biasOff, int bstr, int sIsZero, int KT_H) {
  const int* offsets = meta + 16;
  int ntiles = meta[48];
  int NX = gridDim.x;
  int lid = blockIdx.x + NX * blockIdx.y;
  int Ntot = NX * ntiles;
  if (lid >= Ntot) return;
  int q = Ntot >> 3, r = Ntot & 7;
  int xcd = lid & 7, pos = lid >> 3;
  int nlid = (xcd < r ? xcd * (q + 1) : r * (q + 1) + (xcd - r) * q) + pos;
  int nt = nlid / ntiles;
  int mti = nlid - nt * ntiles;
  int te = meta[64 + mti];
  int e = te & 255, mt = te >> 8;
  int off = offsets[e], cnt = offsets[e + 1] - off;

  // A ring only: 4 slots x 16 KiB = 64 KiB -> 2 blocks/CU
  __shared__ __align__(128) char lds[65536];

  int tid = threadIdx.x, lane = tid & 63, wid = tid >> 6;
  int wr = wid >> 2, wc = wid & 3;
  int fr = lane & 15, fu = lane >> 4;

  const char* srcA = (const char*)Apre + ((size_t)mti * AKT << 14) + (tid << 4);
  const char* pB = (const char*)Bpre +
      ((((size_t)e * BtNT + ntg0 + nt) * BtKT + kt0B) << 14) + ((wc * 4) << 10) + (lane << 4);

#define STAGE_A(Tn) do { \
    char* _d = lds + (((Tn) & 3) << 14) + (tid << 4); \
    const char* _s = srcA + ((size_t)(Tn) << 14); \
    gload16(_s, _d); gload16(_s + 8192, _d + 8192); } while (0)

  f32x4 acc[8][4];
#pragma unroll
  for (int m = 0; m < 8; ++m)
#pragma unroll
    for (int n = 0; n < 4; ++n) acc[m][n] = (f32x4){0.f, 0.f, 0.f, 0.f};

  bf16x8 bx0, bx1, bx2, bx3, by0, by1, by2, by3;

  // prologue: A(0),A(1) -> LDS; B(0) -> X regs
  STAGE_A(0); STAGE_A(1);
  LOADB(bx0, bx1, bx2, bx3, 0);
  VMWAIT(0);
  bar0();

  for (int kt = 0; kt < nk; kt += 2) {
    // ---- even step: compute B(kt)=X, A slot kt&3; load B(kt+1)->Y; stage A(kt+2) ----
    LOADB(by0, by1, by2, by3, kt + 1);              // kt+1 <= nk-1 always (nk even)
    if (kt + 2 < nk) STAGE_A(kt + 2);
    {
      const char* pa = lds + ((kt & 3) << 14) + (wr << 13) + (lane << 4);
      MFMA32(pa, bx0, bx1, bx2, bx3);
    }
    VMWAIT(2);
    bar0();

    // ---- odd step: compute B(kt+1)=Y, A slot (kt+1)&3; load B(kt+2)->X; stage A(kt+3) ----
    if (kt + 2 < nk) LOADB(bx0, bx1, bx2, bx3, kt + 2);
    if (kt + 3 < nk) STAGE_A(kt + 3);
    {
      const char* pa = lds + (((kt + 1) & 3) << 14) + (wr << 13) + (lane << 4);
      MFMA32(pa, by0, by1, by2, by3);
    }
    VMWAIT(2);
    bar0();
  }
#undef STAGE_A

  if (MODE == 0) {
    // write hbuf page in A-pretile layout for MODE1
    unsigned short* page = Hbuf + (size_t)mti * KT_H * 8192;
#pragma unroll
    for (int m = 0; m < 8; ++m) {
#pragma unroll
      for (int r = 0; r < 4; ++r) {
        int row = wr * 128 + m * 16 + fu * 4 + r;
        int gm = mt * 256 + row;
        if (gm < cnt) {
#pragma unroll
          for (int n = 0; n < 4; ++n) {
            int lc = nt * 256 + wc * 64 + n * 16 + fr;
            float v = acc[m][n][r] + bias[e * bstr + biasOff + lc];
            v = v / (1.f + __expf(-v));
            int kt = lc >> 5;
            int idx = (((kt * 16 + (row >> 4)) << 9) +
                       (((row & 15) + (((lc >> 3) & 3) << 4)) << 3) + (lc & 7));
            page[idx] = f2bf(v);
          }
        }
      }
    }
  } else {
#pragma unroll
    for (int m = 0; m < 8; ++m) {
#pragma unroll
      for (int r = 0; r < 4; ++r) {
        int row = wr * 128 + m * 16 + fu * 4 + r;
        int gm = mt * 256 + row;
        if (gm < cnt) {
          int ent = off + gm;
          float wgt = ewgt[ent];
          float* yrow = Ybuf + (size_t)ent * DDIM;
#pragma unroll
          for (int n = 0; n < 4; ++n) {
            int col = nt * 256 + wc * 64 + n * 16 + fr;
            float v = acc[m][n][r];
            if (sIsZero) {
              yrow[col] = (v + bias[e * bstr + col]) * wgt;
            } else {
              yrow[col] += v * wgt;
            }
          }
        }
      }
    }
  }
}

// ---------------- combine: out[t] = ybuf[inv0] (+ ybuf[inv1]) ----------------

__global__ __launch_bounds__(256) void combine(const float* __restrict__ yb,
                                               const int* __restrict__ inv,
                                               float* __restrict__ out) {
  int t = blockIdx.x, c = threadIdx.x;
  int p = inv[2 * t], q2 = inv[2 * t + 1];
  float4 v = ((const float4*)(yb + (size_t)p * DDIM))[c];
  if (q2 >= 0) {
    float4 w = ((const float4*)(yb + (size_t)q2 * DDIM))[c];
    v.x += w.x; v.y += w.y; v.z += w.z; v.w += w.w;
  }
  ((float4*)(out + (size_t)t * DDIM))[c] = v;
}

// ---------------- host launch ----------------

extern "C" void kernel_launch(void* const* d_in, const int* in_sizes, int n_in,
                              void* d_out, int out_size, void* d_ws, size_t ws_size,
                              hipStream_t stream) {
  (void)in_sizes; (void)n_in; (void)out_size;
  const float* x = (const float*)d_in[0];
  const int* eidx = (const int*)d_in[1];
  const float* ew = (const float*)d_in[2];
  const float* w1 = (const float*)d_in[3];
  const float* b1 = (const float*)d_in[4];
  const float* w2 = (const float*)d_in[5];
  const float* b2 = (const float*)d_in[6];
  float* out = (float*)d_out;

  char* w = (char*)d_ws;
  size_t o_meta = 0;
  size_t o_etok = 4096;
  size_t o_ewgt = o_etok + (size_t)MAXENT * 4;
  size_t o_inv  = o_ewgt + (size_t)MAXENT * 4;
  size_t o_xgp  = o_inv + (size_t)TOKENS * 2 * 4;
  size_t o_w1t  = o_xgp + (size_t)MAXTILES * 32 * 16384;
  size_t o_w2t  = o_w1t + (size_t)NEXP * DDIM * HDIM * 2;
  size_t o_yb   = o_w2t + (size_t)NEXP * DDIM * HDIM * 2;
  size_t o_h    = o_yb + (size_t)MAXENT * DDIM * 4;

  int S = 1;
  while (S < 16) {
    size_t need = o_h + (size_t)MAXTILES * ((HDIM / S) >> 5) * 16384;
    if (need <= ws_size) break;
    S *= 2;
  }
  int HC = HDIM / S;
  int KT_H = HC >> 5;

  int* meta = (int*)(w + o_meta);
  int* etok = (int*)(w + o_etok);
  float* ewgt = (float*)(w + o_ewgt);
  int* inv = (int*)(w + o_inv);
  unsigned short* xgp = (unsigned short*)(w + o_xgp);
  unsigned short* w1t = (unsigned short*)(w + o_w1t);
  unsigned short* w2t = (unsigned short*)(w + o_w2t);
  float* ybuf = (float*)(w + o_yb);
  unsigned short* hbuf = (unsigned short*)(w + o_h);

  hipMemsetAsync(w + o_meta, 0, 4096, stream);

  moe_count<<<TOKENS / 256, 256, 0, stream>>>(eidx, meta);
  moe_scan<<<1, 64, 0, stream>>>(meta);
  moe_scatter<<<TOKENS / 256, 256, 0, stream>>>(eidx, ew, meta, etok, ewgt, inv);
  gather_pre<<<dim3(MAXTILES, DDIM / 32), 256, 0, stream>>>(x, etok, meta, xgp);
  pretile_w<<<NEXP * (HDIM >> 8) * (DDIM >> 6), 256, 0, stream>>>(w1, w1t, DDIM, HDIM);
  pretile_w<<<NEXP * (DDIM >> 8) * (HDIM >> 6), 256, 0, stream>>>(w2, w2t, HDIM, DDIM);

  for (int s = 0; s < S; ++s) {
    moe_gemm<0><<<dim3(HC / 256, MAXTILES), 512, 0, stream>>>(
        xgp, w1t, b1, meta, ewgt, hbuf, nullptr,
        /*AKT*/ DDIM >> 5, /*BtNT*/ HDIM >> 8, /*BtKT*/ DDIM >> 5,
        /*ntg0*/ (s * HC) >> 8, /*kt0B*/ 0,
        /*nk*/ DDIM >> 5, /*biasOff*/ s * HC, /*bstr*/ HDIM, 1, KT_H);
    moe_gemm<1><<<dim3(DDIM / 256, MAXTILES), 512, 0, stream>>>(
        hbuf, w2t, b2, meta, ewgt, nullptr, ybuf,
        /*AKT*/ KT_H, /*BtNT*/ DDIM >> 8, /*BtKT*/ HDIM >> 5,
        /*ntg0*/ 0, /*kt0B*/ (s * HC) >> 5,
        /*nk*/ KT_H, /*biasOff*/ 0, /*bstr*/ DDIM, (s == 0) ? 1 : 0, KT_H);
  }
  combine<<<TOKENS, 256, 0, stream>>>(ybuf, inv, out);
}

// Round 11
// 575.957 us; speedup vs baseline: 1.1107x; 1.1107x over previous
//
#include <hip/hip_runtime.h>
#include <hip/hip_bf16.h>
#include <stdint.h>

#define TOKENS 8192
#define DDIM 1024
#define HDIM 4096
#define NEXP 8
#define MAXENT 16384
#define MAXTILES 72

typedef __attribute__((ext_vector_type(4))) float f32x4;
typedef __attribute__((ext_vector_type(8))) short bf16x8;
typedef __attribute__((ext_vector_type(4))) int i32x4;

__device__ __forceinline__ unsigned short f2bf(float f) {
  __hip_bfloat16 h = __float2bfloat16(f);
  return __builtin_bit_cast(unsigned short, h);
}

__device__ __forceinline__ void gload16(const void* g, void* l) {
  __builtin_amdgcn_global_load_lds(
      (const __attribute__((address_space(1))) unsigned int*)g,
      (__attribute__((address_space(3))) unsigned int*)l, 16, 0, 0);
}

__device__ __forceinline__ void bar() {
  asm volatile("" ::: "memory");
  __builtin_amdgcn_sched_barrier(0);
  __builtin_amdgcn_s_barrier();
  __builtin_amdgcn_sched_barrier(0);
  asm volatile("" ::: "memory");
}

#define VMWAIT(N) asm volatile("s_waitcnt vmcnt(" #N ")" ::: "memory")

// ---------------- prep ----------------

__global__ void moe_count(const int* __restrict__ idx, int* __restrict__ meta) {
  int t = blockIdx.x * 256 + threadIdx.x;
  if (t >= TOKENS) return;
  int e0 = idx[2 * t], e1 = idx[2 * t + 1];
  atomicAdd(&meta[e0], 1);
  if (e1 != e0) atomicAdd(&meta[e1], 1);
}

__global__ void moe_scan(int* __restrict__ meta) {
  if (threadIdx.x != 0 || blockIdx.x != 0) return;
  int s = 0;
  for (int e = 0; e < NEXP; ++e) { meta[16 + e] = s; meta[32 + e] = s; s += meta[e]; }
  meta[16 + NEXP] = s;
  int nt = 0;
  for (int e = 0; e < NEXP; ++e) {
    int m = (meta[e] + 255) >> 8;
    for (int t = 0; t < m; ++t) meta[64 + nt++] = e | (t << 8);
  }
  meta[48] = nt;
}

__global__ void moe_scatter(const int* __restrict__ idx, const float* __restrict__ ew,
                            int* __restrict__ meta, int* __restrict__ etok,
                            float* __restrict__ ewgt, int* __restrict__ inv) {
  int t = blockIdx.x * 256 + threadIdx.x;
  if (t >= TOKENS) return;
  int e0 = idx[2 * t], e1 = idx[2 * t + 1];
  float a = ew[2 * t], b = ew[2 * t + 1];
  if (e0 == e1) {
    int p = atomicAdd(&meta[32 + e0], 1);
    etok[p] = t; ewgt[p] = a + b;
    inv[2 * t] = p; inv[2 * t + 1] = -1;
  } else {
    int p = atomicAdd(&meta[32 + e0], 1);
    etok[p] = t; ewgt[p] = a;
    int q = atomicAdd(&meta[32 + e1], 1);
    etok[q] = t; ewgt[q] = b;
    inv[2 * t] = p; inv[2 * t + 1] = q;
  }
}

// ---------------- gather + convert: xg[ent][D] = bf16(x[etok[ent]][D]) ----------------

__global__ __launch_bounds__(256) void gather_x(const float* __restrict__ x,
                                                const int* __restrict__ etok,
                                                const int* __restrict__ meta,
                                                unsigned short* __restrict__ xg) {
  int total = meta[16 + NEXP];
  int ent = blockIdx.x * 2 + (threadIdx.x >> 7);
  if (ent >= total) return;
  int t = threadIdx.x & 127;
  const float4* s = (const float4*)(x + (size_t)etok[ent] * DDIM) + 2 * t;
  float4 a = s[0], b = s[1];
  union { unsigned short h[8]; i32x4 v; } o;
  o.h[0] = f2bf(a.x); o.h[1] = f2bf(a.y); o.h[2] = f2bf(a.z); o.h[3] = f2bf(a.w);
  o.h[4] = f2bf(b.x); o.h[5] = f2bf(b.y); o.h[6] = f2bf(b.z); o.h[7] = f2bf(b.w);
  ((i32x4*)(xg + (size_t)ent * DDIM))[t] = o.v;
}

// src [E][Kdim][Ndim] f32 -> pretile [e][ntile][ktile][chunk(0..31)][lane(0..63)][8] bf16
__global__ __launch_bounds__(256) void pretile_b(const float* __restrict__ src,
                                                 unsigned short* __restrict__ dst,
                                                 int Kdim, int Ndim) {
  __shared__ unsigned short t16[64][266];
  int KT = Kdim >> 6, NT = Ndim >> 8;
  int bid = blockIdx.x;
  int ktile = bid % KT; int rest = bid / KT;
  int ntile = rest % NT; int e = rest / NT;
  const float* s = src + ((size_t)e * Kdim + ((size_t)ktile << 6)) * Ndim + ((size_t)ntile << 8);
  int tid = threadIdx.x;
  int cp = tid & 127, rh = tid >> 7;
#pragma unroll
  for (int rr = 0; rr < 32; ++rr) {
    int r = rh * 32 + rr;
    float2 v = *(const float2*)(s + (size_t)r * Ndim + 2 * cp);
    unsigned int pk = (unsigned int)f2bf(v.x) | ((unsigned int)f2bf(v.y) << 16);
    *(unsigned int*)&t16[r][2 * cp] = pk;
  }
  __syncthreads();
  size_t obase = (((size_t)e * NT + ntile) * KT + ktile) << 11;
#pragma unroll
  for (int it = 0; it < 8; ++it) {
    int u = it * 256 + tid;
    int chunk = u >> 6, lane = u & 63;
    int nl = ((chunk >> 1) << 4) + (lane & 15);
    int kl = ((chunk & 1) << 5) + ((lane >> 4) << 3);
    union { unsigned short h[8]; i32x4 v; } o;
#pragma unroll
    for (int i = 0; i < 8; ++i) o.h[i] = t16[kl + i][nl];
    ((i32x4*)dst)[obase + u] = o.v;
  }
}

// ---- GEMM: 256x256, BK=64, 8 waves, 1 barrier/K-tile, read-ahead pipeline ----
// A: 2-slot ring (row-major XOR-swizzled), LINEAR source (xg or hbuf).
// B: 3-slot ring (fragment-major pretile).
// XCD remap: mti-chunked per XCD, nt snake-fastest (A-page L2-resident per XCD).

#define MF(P, A0, A1, A2, A3)                                                                  \
  do {                                                                                         \
    __builtin_amdgcn_s_setprio(1);                                                             \
    _Pragma("unroll") for (int n = 0; n < 4; ++n)                                              \
        acc[2*(P)][n]   = __builtin_amdgcn_mfma_f32_16x16x32_bf16(A0, bg0[n], acc[2*(P)][n], 0, 0, 0); \
    _Pragma("unroll") for (int n = 0; n < 4; ++n)                                              \
        acc[2*(P)+1][n] = __builtin_amdgcn_mfma_f32_16x16x32_bf16(A2, bg0[n], acc[2*(P)+1][n], 0, 0, 0); \
    _Pragma("unroll") for (int n = 0; n < 4; ++n)                                              \
        acc[2*(P)][n]   = __builtin_amdgcn_mfma_f32_16x16x32_bf16(A1, bg1[n], acc[2*(P)][n], 0, 0, 0); \
    _Pragma("unroll") for (int n = 0; n < 4; ++n)                                              \
        acc[2*(P)+1][n] = __builtin_amdgcn_mfma_f32_16x16x32_bf16(A3, bg1[n], acc[2*(P)+1][n], 0, 0, 0); \
    __builtin_amdgcn_s_setprio(0);                                                             \
  } while (0)

template <int MODE>
__global__ __launch_bounds__(512, 2) void moe_gemm(
    const unsigned short* __restrict__ Abase,   // xg [MAXENT][DDIM] or hbuf [MAXENT][HC]
    const unsigned short* __restrict__ Bpre,
    const float* __restrict__ bias,
    const int* __restrict__ meta,
    const int* __restrict__ etok,
    const float* __restrict__ ewgt,
    unsigned short* __restrict__ Hbuf,
    float* __restrict__ Out,
    int Astride, int BtNT, int BtKT,
    int nbase, int kbase, int Klen,
    int biasStride, int Hstride, int addbias) {
  const int* offsets = meta + 16;
  int ntiles = meta[48];
  int NX = gridDim.x;
  int lid = blockIdx.x + NX * blockIdx.y;
  int Ntot = NX * ntiles;
  if (lid >= Ntot) return;
  int q = Ntot >> 3, r = Ntot & 7;
  int xcd = lid & 7, pos = lid >> 3;
  int nlid = (xcd < r ? xcd * (q + 1) : r * (q + 1) + (xcd - r) * q) + pos;
  // nt-fastest with snake: XCD owns contiguous mti range; A-page stays L2-resident
  // while the 16 B-panels sweep. (R11's single variable vs R7.)
  int mti = nlid / NX;
  int rawnt = nlid - mti * NX;
  int nt = (mti & 1) ? (NX - 1 - rawnt) : rawnt;
  int te = meta[64 + mti];
  int e = te & 255, mt = te >> 8;
  int off = offsets[e], cnt = offsets[e + 1] - off;

  // A: [0,64K) 2 slots x 32 KiB. B: [64K,160K) 3 slots x 32 KiB.
  __shared__ __align__(128) char lds[163840];

  int tid = threadIdx.x;
  int lane = tid & 63, wid = tid >> 6;
  int wr = wid >> 2, wc = wid & 3;
  int fr = lane & 15, fu = lane >> 4;
  int cu0 = fu ^ (fr & 7);

  // ---- A staging sources (linear rows; pre-swizzled source unit) ----
  int rg = (lane >> 3) & 7;
  int g = (lane & 7) ^ rg;
  const char* srcA[2][2];
#pragma unroll
  for (int h = 0; h < 2; ++h) {
#pragma unroll
    for (int j = 0; j < 2; ++j) {
      int rA = wid * 16 + j * 8 + rg;
      int gi = off + mt * 256 + h * 128 + rA;
      if (gi > MAXENT - 1) gi = MAXENT - 1;
      srcA[h][j] = (const char*)(Abase + (size_t)gi * Astride) + g * 16;
    }
  }
  // ---- B staging sources (pretile: linear per wave) ----
  const char* srcB[2][2];
  {
    const char* BpreE = (const char*)Bpre +
        ((((size_t)e * BtNT + (nbase >> 8) + nt) * BtKT + (kbase >> 6)) << 15);
#pragma unroll
    for (int h = 0; h < 2; ++h)
#pragma unroll
      for (int j = 0; j < 2; ++j)
        srcB[h][j] = BpreE + (h << 14) + ((j * 8 + wid) << 10) + (lane << 4);
  }

#define STA(Tn, h) do { \
    char* _d = lds + (((Tn) & 1) << 15) + ((h) << 14) + (wid << 11); \
    gload16(srcA[h][0] + ((size_t)(Tn) << 7), _d); \
    gload16(srcA[h][1] + ((size_t)(Tn) << 7), _d + 1024); } while (0)
#define STB(sl, Tn, h) do { \
    char* _d = lds + 65536 + ((sl) * 32768) + ((h) << 14) + (wid << 10); \
    gload16(srcB[h][0] + ((size_t)(Tn) << 15), _d); \
    gload16(srcB[h][1] + ((size_t)(Tn) << 15), _d + 8192); } while (0)

  f32x4 acc[8][4];
#pragma unroll
  for (int m = 0; m < 8; ++m)
#pragma unroll
    for (int n = 0; n < 4; ++n) acc[m][n] = (f32x4){0.f, 0.f, 0.f, 0.f};

  bf16x8 bg0[4], bg1[4];
  auto rdA = [&](int T, int p, bf16x8& x0, bf16x8& x1, bf16x8& x2, bf16x8& x3) {
    const char* b = lds + ((T & 1) << 15) + (wr << 14) + fr * 128;
    const char* p0 = b + cu0 * 16;
    const char* p1 = b + (cu0 ^ 4) * 16;
    x0 = *(const bf16x8*)(p0 + (2 * p) * 2048);
    x1 = *(const bf16x8*)(p1 + (2 * p) * 2048);
    x2 = *(const bf16x8*)(p0 + (2 * p + 1) * 2048);
    x3 = *(const bf16x8*)(p1 + (2 * p + 1) * 2048);
  };
  auto rdB = [&](int sl) {
    const char* pb = lds + 65536 + sl * 32768 + (wc << 13) + (lane << 4);
#pragma unroll
    for (int n = 0; n < 4; ++n) {
      bg0[n] = *(const bf16x8*)(pb + n * 2048);
      bg1[n] = *(const bf16x8*)(pb + n * 2048 + 1024);
    }
  };

  int nk = Klen >> 6;

  STA(0, 0); STA(0, 1);
  STB(0, 0, 0); STB(0, 0, 1);
  STB(1, 1, 0); STB(1, 1, 1);
  VMWAIT(4);
  bar();

  bf16x8 c0, c1, c2, c3, n0, n1, n2, n3;
  rdA(0, 0, c0, c1, c2, c3);
  rdB(0);

  int bs = 0;
  for (int T = 0; T < nk; ++T) {
    int s1 = (T + 1 < nk), s2 = (T + 2 < nk);
    rdA(T, 1, n0, n1, n2, n3);
    if (s1) STA(T + 1, 0);
    MF(0, c0, c1, c2, c3);
    rdA(T, 2, c0, c1, c2, c3);
    if (s1) STA(T + 1, 1);
    MF(1, n0, n1, n2, n3);
    rdA(T, 3, n0, n1, n2, n3);
    int bs2 = bs >= 1 ? bs - 1 : bs + 2;
    if (s2) { STB(bs2, T + 2, 0); STB(bs2, T + 2, 1); }
    MF(2, c0, c1, c2, c3);
    MF(3, n0, n1, n2, n3);
    if (s2) { VMWAIT(4); } else if (s1) { VMWAIT(0); }
    bar();
    int Tn = s1 ? T + 1 : T;
    int bsn = bs < 2 ? bs + 1 : 0;
    rdA(Tn, 0, c0, c1, c2, c3);
    rdB(s1 ? bsn : bs);
    bs = bsn;
  }
#undef STA
#undef STB

  int colb = nt * 256 + wc * 64;
  if (MODE == 0) {
#pragma unroll
    for (int m = 0; m < 8; ++m) {
#pragma unroll
      for (int r = 0; r < 4; ++r) {
        int row = wr * 128 + m * 16 + fu * 4 + r;
        int gm = mt * 256 + row;
        if (gm < cnt) {
          size_t hrow = (size_t)(off + gm) * Hstride;
#pragma unroll
          for (int n = 0; n < 4; ++n) {
            int col = colb + n * 16 + fr;
            float v = acc[m][n][r] + bias[e * biasStride + nbase + col];
            v = v / (1.f + __expf(-v));
            Hbuf[hrow + col] = f2bf(v);
          }
        }
      }
    }
  } else {
#pragma unroll
    for (int m = 0; m < 8; ++m) {
#pragma unroll
      for (int r = 0; r < 4; ++r) {
        int row = wr * 128 + m * 16 + fu * 4 + r;
        int gm = mt * 256 + row;
        if (gm < cnt) {
          int ent = off + gm;
          int tok = etok[ent];
          float wgt = ewgt[ent];
#pragma unroll
          for (int n = 0; n < 4; ++n) {
            int col = colb + n * 16 + fr;
            float v = acc[m][n][r];
            if (addbias) v += bias[e * biasStride + col];
            atomicAdd(Out + (size_t)tok * DDIM + col, v * wgt);
          }
        }
      }
    }
  }
}

// ---------------- host launch ----------------

extern "C" void kernel_launch(void* const* d_in, const int* in_sizes, int n_in,
                              void* d_out, int out_size, void* d_ws, size_t ws_size,
                              hipStream_t stream) {
  (void)in_sizes; (void)n_in;
  const float* x = (const float*)d_in[0];
  const int* eidx = (const int*)d_in[1];
  const float* ew = (const float*)d_in[2];
  const float* w1 = (const float*)d_in[3];
  const float* b1 = (const float*)d_in[4];
  const float* w2 = (const float*)d_in[5];
  const float* b2 = (const float*)d_in[6];
  float* out = (float*)d_out;

  char* w = (char*)d_ws;
  size_t o_meta = 0;
  size_t o_etok = 4096;
  size_t o_ewgt = o_etok + (size_t)MAXENT * 4;
  size_t o_inv  = o_ewgt + (size_t)MAXENT * 4;
  size_t o_xg   = o_inv + (size_t)TOKENS * 2 * 4;
  size_t o_w1t  = o_xg + (size_t)MAXENT * DDIM * 2;
  size_t o_w2t  = o_w1t + (size_t)DDIM * HDIM * NEXP * 2;
  size_t o_h    = o_w2t + (size_t)DDIM * HDIM * NEXP * 2;

  int S = 1;
  while (S < 16) {
    size_t need = o_h + (size_t)MAXENT * (HDIM / S) * 2;
    if (need <= ws_size) break;
    S *= 2;
  }
  int HC = HDIM / S;

  int* meta = (int*)(w + o_meta);
  int* etok = (int*)(w + o_etok);
  float* ewgt = (float*)(w + o_ewgt);
  int* inv = (int*)(w + o_inv);
  unsigned short* xg = (unsigned short*)(w + o_xg);
  unsigned short* w1t = (unsigned short*)(w + o_w1t);
  unsigned short* w2t = (unsigned short*)(w + o_w2t);
  unsigned short* hbuf = (unsigned short*)(w + o_h);

  hipMemsetAsync(w + o_meta, 0, 4096, stream);
  hipMemsetAsync(d_out, 0, (size_t)out_size * 4, stream);

  moe_count<<<TOKENS / 256, 256, 0, stream>>>(eidx, meta);
  moe_scan<<<1, 64, 0, stream>>>(meta);
  moe_scatter<<<TOKENS / 256, 256, 0, stream>>>(eidx, ew, meta, etok, ewgt, inv);
  gather_x<<<MAXENT / 2, 256, 0, stream>>>(x, etok, meta, xg);
  pretile_b<<<NEXP * (HDIM >> 8) * (DDIM >> 6), 256, 0, stream>>>(w1, w1t, DDIM, HDIM);
  pretile_b<<<NEXP * (DDIM >> 8) * (HDIM >> 6), 256, 0, stream>>>(w2, w2t, HDIM, DDIM);

  for (int s = 0; s < S; ++s) {
    moe_gemm<0><<<dim3(HC / 256, MAXTILES, 1), 512, 0, stream>>>(
        xg, w1t, b1, meta, etok, ewgt, hbuf, nullptr,
        DDIM, HDIM / 256, DDIM / 64, s * HC, 0, DDIM, HDIM, HC, 0);
    moe_gemm<1><<<dim3(DDIM / 256, MAXTILES, 1), 512, 0, stream>>>(
        hbuf, w2t, b2, meta, etok, ewgt, nullptr, out,
        HC, DDIM / 256, HDIM / 64, 0, s * HC, HC, DDIM, 0, (s == 0) ? 1 : 0);
  }
}